// Round 8
// baseline (72.229 us; speedup 1.0000x reference)
//
#include <hip/hip_runtime.h>
#include <hip/hip_bf16.h>

#define N_CELLS 4096
#define CHUNK 8
#define HID 1024

typedef float fvec4 __attribute__((ext_vector_type(4)));

// non-temporal float4 load: stream, do not retain in cache hierarchy
__device__ __forceinline__ fvec4 nt_load4(const float* p) {
    return __builtin_nontemporal_load(reinterpret_cast<const fvec4*>(p));
}

__global__ __launch_bounds__(256) void cell_mlp_kernel(
    const float* __restrict__ x,
    const float* __restrict__ W1,
    const float* __restrict__ b1,
    const float* __restrict__ W2,
    const float* __restrict__ b2,
    float* __restrict__ out)
{
    const int c = blockIdx.x;      // cell index
    const int t = threadIdx.x;     // 0..255

    // x broadcast: 2 x float4 (same line for all threads -> L1 broadcast)
    const float* xc = x + (size_t)c * CHUNK;
    float4 xlo = *reinterpret_cast<const float4*>(xc);
    float4 xhi = *reinterpret_cast<const float4*>(xc + 4);

    // bias for hidden units 4t..4t+3  (cacheable: part of the L3-resident set)
    float4 bb = *reinterpret_cast<const float4*>(b1 + (size_t)c * HID + 4 * t);

    // W1: [cell][k=0..7][h] -> float4 at (k*HID + 4t), coalesced across lanes
    // CACHEABLE: W1+b1 = 144 MB < 256 MiB L3 -> stays resident across replays
    const float* W1c = W1 + (size_t)c * CHUNK * HID + 4 * t;
    float4 w1r[CHUNK];
#pragma unroll
    for (int k = 0; k < CHUNK; ++k)
        w1r[k] = *reinterpret_cast<const float4*>(W1c + k * HID);

    // W2: [cell][h][j=0..7] -> thread owns rows 4t..4t+3 = 128 contiguous B
    // NON-TEMPORAL: stream from HBM, don't evict the W1 working set from L3
    const float* W2c = W2 + (size_t)c * HID * CHUNK + (size_t)(4 * t) * CHUNK;
    fvec4 w2r[CHUNK];
#pragma unroll
    for (int i = 0; i < CHUNK; ++i)
        w2r[i] = nt_load4(W2c + 4 * i);

    // pin the load issue order: nothing crosses this point
    __builtin_amdgcn_sched_barrier(0);

    // ---- layer 1 ----
    const float xv[CHUNK] = {xlo.x, xlo.y, xlo.z, xlo.w,
                             xhi.x, xhi.y, xhi.z, xhi.w};
    float acc0 = bb.x, acc1 = bb.y, acc2 = bb.z, acc3 = bb.w;
#pragma unroll
    for (int k = 0; k < CHUNK; ++k) {
        acc0 += xv[k] * w1r[k].x;
        acc1 += xv[k] * w1r[k].y;
        acc2 += xv[k] * w1r[k].z;
        acc3 += xv[k] * w1r[k].w;
    }

    const float hv[4] = {tanhf(acc0), tanhf(acc1), tanhf(acc2), tanhf(acc3)};

    // ---- layer 2 ----
    float y[CHUNK];
#pragma unroll
    for (int j = 0; j < CHUNK; ++j) y[j] = 0.0f;

#pragma unroll
    for (int i = 0; i < 4; ++i) {
        const fvec4 a = w2r[2 * i];
        const fvec4 b = w2r[2 * i + 1];
        y[0] += hv[i] * a[0];
        y[1] += hv[i] * a[1];
        y[2] += hv[i] * a[2];
        y[3] += hv[i] * a[3];
        y[4] += hv[i] * b[0];
        y[5] += hv[i] * b[1];
        y[6] += hv[i] * b[2];
        y[7] += hv[i] * b[3];
    }

    // ---- reduce across the 64-lane wave ----
#pragma unroll
    for (int j = 0; j < CHUNK; ++j) {
#pragma unroll
        for (int off = 32; off > 0; off >>= 1) {
            y[j] += __shfl_down(y[j], off, 64);
        }
    }

    // ---- cross-wave reduce via LDS (4 waves per block) ----
    __shared__ float red[4][CHUNK];
    const int wave = t >> 6;
    const int lane = t & 63;
    if (lane == 0) {
#pragma unroll
        for (int j = 0; j < CHUNK; ++j) red[wave][j] = y[j];
    }
    __syncthreads();

    if (t < CHUNK) {
        float s = red[0][t] + red[1][t] + red[2][t] + red[3][t]
                + b2[(size_t)c * CHUNK + t];
        out[(size_t)c * CHUNK + t] = s;
    }
}

extern "C" void kernel_launch(void* const* d_in, const int* in_sizes, int n_in,
                              void* d_out, int out_size, void* d_ws, size_t ws_size,
                              hipStream_t stream) {
    const float* x  = (const float*)d_in[0];
    const float* W1 = (const float*)d_in[1];
    const float* b1 = (const float*)d_in[2];
    const float* W2 = (const float*)d_in[3];
    const float* b2 = (const float*)d_in[4];
    float* out = (float*)d_out;

    cell_mlp_kernel<<<N_CELLS, 256, 0, stream>>>(x, W1, b1, W2, b2, out);
}

// Round 11
// 46.124 us; speedup vs baseline: 1.5660x; 1.5660x over previous
//
#include <hip/hip_runtime.h>
#include <hip/hip_bf16.h>

#define N_CELLS 4096
#define CHUNK 8
#define HID 1024

// 2 cells per block: doubles per-wave load-level parallelism to discriminate
// "mixed L3/HBM throughput ceiling (~5.9 TB/s)" vs "insufficient MLP".
__global__ __launch_bounds__(256) void cell_mlp_kernel(
    const float* __restrict__ x,
    const float* __restrict__ W1,
    const float* __restrict__ b1,
    const float* __restrict__ W2,
    const float* __restrict__ b2,
    float* __restrict__ out)
{
    const int bid = blockIdx.x;
    const int t   = threadIdx.x;   // 0..255
    const int c0  = 2 * bid;
    const int c1  = 2 * bid + 1;

    // ---------- issue ALL loads for BOTH cells up front ----------
    // cell 0
    const float* xc0 = x + (size_t)c0 * CHUNK;
    float4 x0lo = *reinterpret_cast<const float4*>(xc0);
    float4 x0hi = *reinterpret_cast<const float4*>(xc0 + 4);
    float4 bb0  = *reinterpret_cast<const float4*>(b1 + (size_t)c0 * HID + 4 * t);

    const float* W1c0 = W1 + (size_t)c0 * CHUNK * HID + 4 * t;
    float4 w1a[CHUNK];
#pragma unroll
    for (int k = 0; k < CHUNK; ++k)
        w1a[k] = *reinterpret_cast<const float4*>(W1c0 + k * HID);

    const float* W2c0 = W2 + (size_t)c0 * HID * CHUNK + (size_t)(4 * t) * CHUNK;
    float4 w2a[CHUNK];
#pragma unroll
    for (int i = 0; i < CHUNK; ++i)
        w2a[i] = *reinterpret_cast<const float4*>(W2c0 + 4 * i);

    // cell 1
    const float* xc1 = x + (size_t)c1 * CHUNK;
    float4 x1lo = *reinterpret_cast<const float4*>(xc1);
    float4 x1hi = *reinterpret_cast<const float4*>(xc1 + 4);
    float4 bb1  = *reinterpret_cast<const float4*>(b1 + (size_t)c1 * HID + 4 * t);

    const float* W1c1 = W1 + (size_t)c1 * CHUNK * HID + 4 * t;
    float4 w1b[CHUNK];
#pragma unroll
    for (int k = 0; k < CHUNK; ++k)
        w1b[k] = *reinterpret_cast<const float4*>(W1c1 + k * HID);

    const float* W2c1 = W2 + (size_t)c1 * HID * CHUNK + (size_t)(4 * t) * CHUNK;
    float4 w2b[CHUNK];
#pragma unroll
    for (int i = 0; i < CHUNK; ++i)
        w2b[i] = *reinterpret_cast<const float4*>(W2c1 + 4 * i);

    // ---------- compute cell 0 ----------
    float y0[CHUNK], y1[CHUNK];
    {
        const float xv[CHUNK] = {x0lo.x, x0lo.y, x0lo.z, x0lo.w,
                                 x0hi.x, x0hi.y, x0hi.z, x0hi.w};
        float a0 = bb0.x, a1 = bb0.y, a2 = bb0.z, a3 = bb0.w;
#pragma unroll
        for (int k = 0; k < CHUNK; ++k) {
            a0 += xv[k] * w1a[k].x;
            a1 += xv[k] * w1a[k].y;
            a2 += xv[k] * w1a[k].z;
            a3 += xv[k] * w1a[k].w;
        }
        const float hv[4] = {tanhf(a0), tanhf(a1), tanhf(a2), tanhf(a3)};
#pragma unroll
        for (int j = 0; j < CHUNK; ++j) y0[j] = 0.0f;
#pragma unroll
        for (int i = 0; i < 4; ++i) {
            const float4 a = w2a[2 * i];
            const float4 b = w2a[2 * i + 1];
            y0[0] += hv[i] * a.x;  y0[1] += hv[i] * a.y;
            y0[2] += hv[i] * a.z;  y0[3] += hv[i] * a.w;
            y0[4] += hv[i] * b.x;  y0[5] += hv[i] * b.y;
            y0[6] += hv[i] * b.z;  y0[7] += hv[i] * b.w;
        }
    }

    // ---------- compute cell 1 ----------
    {
        const float xv[CHUNK] = {x1lo.x, x1lo.y, x1lo.z, x1lo.w,
                                 x1hi.x, x1hi.y, x1hi.z, x1hi.w};
        float a0 = bb1.x, a1 = bb1.y, a2 = bb1.z, a3 = bb1.w;
#pragma unroll
        for (int k = 0; k < CHUNK; ++k) {
            a0 += xv[k] * w1b[k].x;
            a1 += xv[k] * w1b[k].y;
            a2 += xv[k] * w1b[k].z;
            a3 += xv[k] * w1b[k].w;
        }
        const float hv[4] = {tanhf(a0), tanhf(a1), tanhf(a2), tanhf(a3)};
#pragma unroll
        for (int j = 0; j < CHUNK; ++j) y1[j] = 0.0f;
#pragma unroll
        for (int i = 0; i < 4; ++i) {
            const float4 a = w2b[2 * i];
            const float4 b = w2b[2 * i + 1];
            y1[0] += hv[i] * a.x;  y1[1] += hv[i] * a.y;
            y1[2] += hv[i] * a.z;  y1[3] += hv[i] * a.w;
            y1[4] += hv[i] * b.x;  y1[5] += hv[i] * b.y;
            y1[6] += hv[i] * b.z;  y1[7] += hv[i] * b.w;
        }
    }

    // ---------- wave reduce both cells ----------
#pragma unroll
    for (int j = 0; j < CHUNK; ++j) {
#pragma unroll
        for (int off = 32; off > 0; off >>= 1) {
            y0[j] += __shfl_down(y0[j], off, 64);
            y1[j] += __shfl_down(y1[j], off, 64);
        }
    }

    // ---------- cross-wave reduce via LDS ----------
    __shared__ float red[2][4][CHUNK];
    const int wave = t >> 6;
    const int lane = t & 63;
    if (lane == 0) {
#pragma unroll
        for (int j = 0; j < CHUNK; ++j) {
            red[0][wave][j] = y0[j];
            red[1][wave][j] = y1[j];
        }
    }
    __syncthreads();

    if (t < 2 * CHUNK) {
        const int cc = t >> 3;            // 0 or 1
        const int j  = t & 7;
        const int c  = 2 * bid + cc;
        float s = red[cc][0][j] + red[cc][1][j] + red[cc][2][j] + red[cc][3][j]
                + b2[(size_t)c * CHUNK + j];
        out[(size_t)c * CHUNK + j] = s;
    }
}

extern "C" void kernel_launch(void* const* d_in, const int* in_sizes, int n_in,
                              void* d_out, int out_size, void* d_ws, size_t ws_size,
                              hipStream_t stream) {
    const float* x  = (const float*)d_in[0];
    const float* W1 = (const float*)d_in[1];
    const float* b1 = (const float*)d_in[2];
    const float* W2 = (const float*)d_in[3];
    const float* b2 = (const float*)d_in[4];
    float* out = (float*)d_out;

    cell_mlp_kernel<<<N_CELLS / 2, 256, 0, stream>>>(x, W1, b1, W2, b2, out);
}